// Round 3
// baseline (465.723 us; speedup 1.0000x reference)
//
#include <hip/hip_runtime.h>
#include <math.h>

#define B_ 16
#define N_ 4096

typedef __attribute__((ext_vector_type(8))) short short8v;
typedef __attribute__((ext_vector_type(4))) float f32x4;

__device__ __forceinline__ unsigned short f2bf(float f) {
  unsigned int u = __float_as_uint(f);
  return (unsigned short)((u + 0x7FFFu + ((u >> 16) & 1u)) >> 16);
}

// convert 8 consecutive fp32 -> bf16x8 fragment
__device__ __forceinline__ short8v cvt8f(const float* p) {
  float4 a = *reinterpret_cast<const float4*>(p);
  float4 b = *reinterpret_cast<const float4*>(p + 4);
  short8v r;
  r[0] = (short)f2bf(a.x); r[1] = (short)f2bf(a.y);
  r[2] = (short)f2bf(a.z); r[3] = (short)f2bf(a.w);
  r[4] = (short)f2bf(b.x); r[5] = (short)f2bf(b.y);
  r[6] = (short)f2bf(b.z); r[7] = (short)f2bf(b.w);
  return r;
}

// ---------------- square weights -> bf16 (no reorder) ----------------------
__global__ __launch_bounds__(256) void cvt_w(const float* __restrict__ a,
    const float* __restrict__ b, const float* __restrict__ c,
    const float* __restrict__ d, unsigned short* __restrict__ wa,
    unsigned short* __restrict__ wb, unsigned short* __restrict__ wc,
    unsigned short* __restrict__ wd) {
  int i = blockIdx.x * 256 + threadIdx.x;
  int j = i & 16383;
  if (i < 16384) wa[j] = f2bf(a[j]);
  else if (i < 32768) wb[j] = f2bf(b[j]);
  else if (i < 49152) wc[j] = f2bf(c[j]);
  else wd[j] = f2bf(d[j]);
}

// ------------- MFMA GEMM: out[r][c] = sum_k A[r][k] * W[c][k] --------------
// A fp32 row-major K=128 (converted in-register), W bf16 [128][128], out fp32.
template <bool HAS_BIAS>
__global__ __launch_bounds__(256) void gemm_mfma(const float* __restrict__ A,
    const unsigned short* __restrict__ W, const float* __restrict__ bias,
    float* __restrict__ out) {
  const int t = threadIdx.x;
  const int wid = t >> 6, lane = t & 63;
  const int lrow = lane & 15, lk = (lane >> 4) << 3;
  const int r0 = blockIdx.x * 128 + wid * 32;
  f32x4 acc[2][8];
#pragma unroll
  for (int m = 0; m < 2; m++)
#pragma unroll
    for (int n = 0; n < 8; n++) acc[m][n] = (f32x4)(0.f);
#pragma unroll
  for (int k0 = 0; k0 < 128; k0 += 32) {
    short8v a[2], bf[8];
#pragma unroll
    for (int m = 0; m < 2; m++)
      a[m] = cvt8f(A + (size_t)(r0 + m * 16 + lrow) * 128 + k0 + lk);
#pragma unroll
    for (int n = 0; n < 8; n++)
      bf[n] = *reinterpret_cast<const short8v*>(
          W + (size_t)(n * 16 + lrow) * 128 + k0 + lk);
#pragma unroll
    for (int m = 0; m < 2; m++)
#pragma unroll
      for (int n = 0; n < 8; n++)
        acc[m][n] = __builtin_amdgcn_mfma_f32_16x16x32_bf16(a[m], bf[n],
                                                            acc[m][n], 0, 0, 0);
  }
  const int rr = (lane >> 4) << 2;
#pragma unroll
  for (int m = 0; m < 2; m++)
#pragma unroll
    for (int n = 0; n < 8; n++) {
      int c = n * 16 + lrow;
      float bv = HAS_BIAS ? bias[c] : 0.f;
#pragma unroll
      for (int j = 0; j < 4; j++)
        out[(size_t)(r0 + m * 16 + rr + j) * 128 + c] = acc[m][n][j] + bv;
    }
}

// ---------- patchify conv as MFMA gather-GEMM, K-split partials ------------
// x fp32 (b,4096,128); W = RAW fp32 sr weights (co, ci, kh, kw) — round-1
// k-ordering: k = ci*SS + kh*SRV + kw (W fragments contiguous in raw layout).
template <int SRV, int KSP>
__global__ __launch_bounds__(256) void convgemm_mfma(
    const float* __restrict__ x, const float* __restrict__ W,
    float* __restrict__ part) {
  constexpr int WP = 64 / SRV;
  constexpr int M = WP * WP;
  constexpr int ROWS = B_ * M;
  constexpr int SS = SRV * SRV;
  constexpr int KTOT = 128 * SS;
  constexpr int LSS = (SRV == 8) ? 6 : 4;
  constexpr int LSR = (SRV == 8) ? 3 : 2;
  constexpr int LM = (SRV == 8) ? 6 : 8;
  constexpr int LWP = (SRV == 8) ? 3 : 4;
  const int t = threadIdx.x;
  const int wid = t >> 6, lane = t & 63;
  const int lrow = lane & 15, lk = (lane >> 4) << 3;
  const int r0 = blockIdx.x * 128 + wid * 32;
  const int kb0 = blockIdx.y * KSP;
  int rbase[2], pixoff[2];
#pragma unroll
  for (int m = 0; m < 2; m++) {
    int row = r0 + m * 16 + lrow;
    int b = row >> LM, p = row & (M - 1);
    int ph = p >> LWP, pw = p & (WP - 1);
    rbase[m] = b << 12;
    pixoff[m] = (ph * SRV) * 64 + pw * SRV;
  }
  f32x4 acc[2][8];
#pragma unroll
  for (int m = 0; m < 2; m++)
#pragma unroll
    for (int n = 0; n < 8; n++) acc[m][n] = (f32x4)(0.f);
  for (int k0 = 0; k0 < KSP; k0 += 32) {
    int k = kb0 + k0 + lk;          // multiple of 8
    int ci = k >> LSS;
    int rem = k & (SS - 1);         // multiple of 8; rem+7 < SS
    short8v a[2], bf[8];
#pragma unroll
    for (int m = 0; m < 2; m++) {
      short8v av;
#pragma unroll
      for (int j = 0; j < 8; j++) {
        int rj = rem + j;
        int kh = rj >> LSR, kw = rj & (SRV - 1);
        av[j] = (short)f2bf(
            x[((size_t)(rbase[m] + pixoff[m] + kh * 64 + kw)) * 128 + ci]);
      }
      a[m] = av;
    }
#pragma unroll
    for (int n = 0; n < 8; n++)
      bf[n] = cvt8f(W + (size_t)(n * 16 + lrow) * KTOT + k);
#pragma unroll
    for (int m = 0; m < 2; m++)
#pragma unroll
      for (int n = 0; n < 8; n++)
        acc[m][n] = __builtin_amdgcn_mfma_f32_16x16x32_bf16(a[m], bf[n],
                                                            acc[m][n], 0, 0, 0);
  }
  const int rr = (lane >> 4) << 2;
#pragma unroll
  for (int m = 0; m < 2; m++)
#pragma unroll
    for (int n = 0; n < 8; n++) {
      int c = n * 16 + lrow;
#pragma unroll
      for (int j = 0; j < 4; j++)
        part[((size_t)blockIdx.y * ROWS + r0 + m * 16 + rr + j) * 128 + c] =
            acc[m][n][j];
    }
}

// ---- reduce K-split partials + conv bias, LayerNorm(128) + exact GELU -----
__global__ __launch_bounds__(128) void ln_gelu(const float* __restrict__ part,
    int nsplit, int rows, const float* __restrict__ cb,
    const float* __restrict__ g, const float* __restrict__ be,
    float* __restrict__ out) {
  const int row = blockIdx.x;
  const int t = threadIdx.x;
  float v = cb[t];
  for (int s = 0; s < nsplit; s++)
    v += part[((size_t)s * rows + row) * 128 + t];
  float sv = v, sq = v * v;
#pragma unroll
  for (int off = 32; off > 0; off >>= 1) {
    sv += __shfl_down(sv, off, 64);
    sq += __shfl_down(sq, off, 64);
  }
  __shared__ float red0[2], red1[2];
  if ((t & 63) == 0) {
    red0[t >> 6] = sv;
    red1[t >> 6] = sq;
  }
  __syncthreads();
  float mean = (red0[0] + red0[1]) * (1.f / 128.f);
  float var = (red1[0] + red1[1]) * (1.f / 128.f) - mean * mean;
  float y = (v - mean) * rsqrtf(var + 1e-5f) * g[t] + be[t];
  out[(size_t)row * 128 + t] = y * 0.5f * (1.f + erff(y * 0.70710678118f));
}

// --------- depthwise 3x3 (pad 1) on v; v' = v + conv (fp32) ---------------
template <int WP>
__global__ __launch_bounds__(256) void dwconv(const float* __restrict__ kv,
    const float* __restrict__ lw, const float* __restrict__ lb,
    float* __restrict__ vp) {
  constexpr int M = WP * WP;
  constexpr int LM = (WP == 8) ? 6 : 8;
  constexpr int LWPc = (WP == 8) ? 3 : 4;
  int idx = blockIdx.x * 256 + threadIdx.x;
  int ch = idx & 63;
  int rest = idx >> 6;
  int m = rest & (M - 1);
  int bb = rest >> LM;
  int y = m >> LWPc, x0 = m & (WP - 1);
  float s = lb[ch];
#pragma unroll
  for (int ky = 0; ky < 3; ky++) {
    int yy = y + ky - 1;
    if (yy < 0 || yy >= WP) continue;
#pragma unroll
    for (int kx = 0; kx < 3; kx++) {
      int xx = x0 + kx - 1;
      if (xx < 0 || xx >= WP) continue;
      s += kv[((size_t)(bb * M + yy * WP + xx)) * 128 + 64 + ch] *
           lw[ch * 9 + ky * 3 + kx];
    }
  }
  vp[idx] = kv[((size_t)(bb * M + m)) * 128 + 64 + ch] + s;
}

// ------------- fused attention (round-1 exact, all fp32) -------------------
template <int M, int QOFF>
__global__ __launch_bounds__(256) void attn(const float* __restrict__ q,
    const float* __restrict__ kv, const float* __restrict__ vp,
    float* __restrict__ xcat) {
  __shared__ float k_s[M][32];
  __shared__ float v_s[M][32];
  const int t = threadIdx.x;
  const int h = blockIdx.y, b = blockIdx.z;
  const size_t bm = (size_t)b * M;
  for (int e = t; e < M * 32; e += 256) {
    int m = e >> 5, d = e & 31;
    k_s[m][d] = kv[(bm + m) * 128 + h * 32 + d];
    v_s[m][d] = vp[(bm + m) * 64 + h * 32 + d];
  }
  __syncthreads();
  const int n = blockIdx.x * 256 + t;
  const float4* qv =
      reinterpret_cast<const float4*>(&q[((size_t)b * N_ + n) * 128 + QOFF + h * 32]);
  float4 q4[8];
#pragma unroll
  for (int i = 0; i < 8; i++) q4[i] = qv[i];
  float l = 0.f;
  float acc[32];
#pragma unroll
  for (int i = 0; i < 32; i++) acc[i] = 0.f;
  const float scale = 0.17677669529663687f;  // 1/sqrt(32)
  for (int m = 0; m < M; m++) {
    const float4* kr = reinterpret_cast<const float4*>(&k_s[m][0]);
    float s = 0.f;
#pragma unroll
    for (int i = 0; i < 8; i++) {
      float4 k4 = kr[i];
      s += q4[i].x * k4.x + q4[i].y * k4.y + q4[i].z * k4.z + q4[i].w * k4.w;
    }
    float p = __expf(s * scale);
    l += p;
    const float4* vr = reinterpret_cast<const float4*>(&v_s[m][0]);
#pragma unroll
    for (int i = 0; i < 8; i++) {
      float4 v4 = vr[i];
      acc[4 * i + 0] += p * v4.x;
      acc[4 * i + 1] += p * v4.y;
      acc[4 * i + 2] += p * v4.z;
      acc[4 * i + 3] += p * v4.w;
    }
  }
  float inv = 1.f / l;
  float4* orow =
      reinterpret_cast<float4*>(&xcat[((size_t)b * N_ + n) * 128 + QOFF + h * 32]);
#pragma unroll
  for (int i = 0; i < 8; i++) {
    float4 o;
    o.x = acc[4 * i + 0] * inv;
    o.y = acc[4 * i + 1] * inv;
    o.z = acc[4 * i + 2] * inv;
    o.w = acc[4 * i + 3] * inv;
    orow[i] = o;
  }
}

extern "C" void kernel_launch(void* const* d_in, const int* in_sizes, int n_in,
                              void* d_out, int out_size, void* d_ws,
                              size_t ws_size, hipStream_t stream) {
  (void)in_sizes; (void)n_in; (void)out_size; (void)ws_size;
  const float* x      = (const float*)d_in[0];
  const float* q_w    = (const float*)d_in[1];
  const float* sr1_w  = (const float*)d_in[2];
  const float* sr1_b  = (const float*)d_in[3];
  const float* n1_g   = (const float*)d_in[4];
  const float* n1_b   = (const float*)d_in[5];
  const float* sr2_w  = (const float*)d_in[6];
  const float* sr2_b  = (const float*)d_in[7];
  const float* n2_g   = (const float*)d_in[8];
  const float* n2_b   = (const float*)d_in[9];
  const float* kv1_w  = (const float*)d_in[10];
  const float* kv2_w  = (const float*)d_in[11];
  const float* lc1_w  = (const float*)d_in[12];
  const float* lc1_b  = (const float*)d_in[13];
  const float* lc2_w  = (const float*)d_in[14];
  const float* lc2_b  = (const float*)d_in[15];
  const float* proj_w = (const float*)d_in[16];
  const float* proj_b = (const float*)d_in[17];

  char* w = (char*)d_ws;
  unsigned short* wq    = (unsigned short*)(w);             // 32 KB
  unsigned short* wkv1  = (unsigned short*)(w + 32768);
  unsigned short* wkv2  = (unsigned short*)(w + 65536);
  unsigned short* wproj = (unsigned short*)(w + 98304);     // ends 131072
  float* qbuf = (float*)(w + 131072);                       // 33.55 MB
  float* xcat = (float*)(w + 33685504);                     // 33.55 MB
  float* t1   = (float*)(w + 67239936);                     // 512 KB
  float* t2   = (float*)(w + 67764224);                     // 2 MB
  float* kv1  = (float*)(w + 69861376);                     // 512 KB
  float* kv2  = (float*)(w + 70385664);                     // 2 MB
  float* v1p  = (float*)(w + 72482816);                     // 256 KB
  float* v2p  = (float*)(w + 72744960);                     // 1 MB -> 73793536
  // conv partials alias xcat (consumed by ln_gelu before attn writes xcat)
  float* part1 = xcat;              // 8 * 131072 floats
  float* part2 = xcat + 2097152;    // 4 * 524288 floats

  cvt_w<<<256, 256, 0, stream>>>(q_w, kv1_w, kv2_w, proj_w, wq, wkv1, wkv2, wproj);
  // q = x @ q_w^T  (fp32 out)
  gemm_mfma<false><<<512, 256, 0, stream>>>(x, wq, nullptr, qbuf);
  // patchify convs (gather MFMA GEMM on raw weights, K-split partials)
  convgemm_mfma<8, 1024><<<dim3(8, 8), 256, 0, stream>>>(x, sr1_w, part1);
  convgemm_mfma<4, 512><<<dim3(32, 4), 256, 0, stream>>>(x, sr2_w, part2);
  // bias + LN + GELU (fp32)
  ln_gelu<<<1024, 128, 0, stream>>>(part1, 8, 1024, sr1_b, n1_g, n1_b, t1);
  ln_gelu<<<4096, 128, 0, stream>>>(part2, 4, 4096, sr2_b, n2_g, n2_b, t2);
  // kv projections
  gemm_mfma<false><<<8, 256, 0, stream>>>(t1, wkv1, nullptr, kv1);
  gemm_mfma<false><<<32, 256, 0, stream>>>(t2, wkv2, nullptr, kv2);
  // local depthwise conv on v
  dwconv<8><<<256, 256, 0, stream>>>(kv1, lc1_w, lc1_b, v1p);
  dwconv<16><<<1024, 256, 0, stream>>>(kv2, lc2_w, lc2_b, v2p);
  // fused attention (fp32)
  attn<64, 0><<<dim3(16, 2, 16), 256, 0, stream>>>(qbuf, kv1, v1p, xcat);
  attn<256, 64><<<dim3(16, 2, 16), 256, 0, stream>>>(qbuf, kv2, v2p, xcat);
  // output projection
  gemm_mfma<true><<<512, 256, 0, stream>>>(xcat, wproj, proj_b, (float*)d_out);
}

// Round 7
// 257.235 us; speedup vs baseline: 1.8105x; 1.8105x over previous
//
#include <hip/hip_runtime.h>
#include <math.h>

#define B_ 16
#define N_ 4096

typedef __attribute__((ext_vector_type(8))) short short8v;
typedef __attribute__((ext_vector_type(4))) short short4v;
typedef __attribute__((ext_vector_type(4))) float f32x4;

__device__ __forceinline__ unsigned short f2bf(float f) {
  unsigned int u = __float_as_uint(f);
  return (unsigned short)((u + 0x7FFFu + ((u >> 16) & 1u)) >> 16);
}

// pack two fp32 -> one dword of two bf16 (lo = first, hi = second)
__device__ __forceinline__ unsigned int pk2(float a, float b) {
  return (unsigned int)f2bf(a) | ((unsigned int)f2bf(b) << 16);
}

// convert 8 consecutive fp32 -> bf16x8 fragment
__device__ __forceinline__ short8v cvt8f(const float* p) {
  float4 a = *reinterpret_cast<const float4*>(p);
  float4 b = *reinterpret_cast<const float4*>(p + 4);
  short8v r;
  r[0] = (short)f2bf(a.x); r[1] = (short)f2bf(a.y);
  r[2] = (short)f2bf(a.z); r[3] = (short)f2bf(a.w);
  r[4] = (short)f2bf(b.x); r[5] = (short)f2bf(b.y);
  r[6] = (short)f2bf(b.z); r[7] = (short)f2bf(b.w);
  return r;
}

// ---------------- square weights -> bf16 (R3 exact) ------------------------
__global__ __launch_bounds__(256) void cvt_w(const float* __restrict__ a,
    const float* __restrict__ b, const float* __restrict__ c,
    const float* __restrict__ d, unsigned short* __restrict__ wa,
    unsigned short* __restrict__ wb, unsigned short* __restrict__ wc,
    unsigned short* __restrict__ wd) {
  int i = blockIdx.x * 256 + threadIdx.x;
  int j = i & 16383;
  if (i < 16384) wa[j] = f2bf(a[j]);
  else if (i < 32768) wb[j] = f2bf(b[j]);
  else if (i < 49152) wc[j] = f2bf(c[j]);
  else wd[j] = f2bf(d[j]);
}

// ---- x (b,4096,128) fp32 -> xT (b,128,4096) bf16: xT[b][c][p] = x[b][p][c] --
// LDS-tiled 32 pixels x 128 ch, padded stride 132.
__global__ __launch_bounds__(256) void transpose_bf(const float* __restrict__ x,
    unsigned short* __restrict__ xT) {
  __shared__ float lds[32 * 132];
  const int t = threadIdx.x;
  const int b = blockIdx.x >> 7, pt = blockIdx.x & 127;
  const int ptile = pt * 32;
  for (int i = t; i < 1024; i += 256) {
    int p = i >> 5, c4 = (i & 31) << 2;
    *reinterpret_cast<float4*>(&lds[p * 132 + c4]) =
        *reinterpret_cast<const float4*>(
            x + ((size_t)(b * 4096 + ptile + p)) * 128 + c4);
  }
  __syncthreads();
  const int c = t >> 1, p0 = (t & 1) * 16;
  unsigned short* dst = xT + (size_t)b * 524288 + c * 4096 + ptile + p0;
  uint4 u0, u1;
  u0.x = pk2(lds[(p0 + 0) * 132 + c], lds[(p0 + 1) * 132 + c]);
  u0.y = pk2(lds[(p0 + 2) * 132 + c], lds[(p0 + 3) * 132 + c]);
  u0.z = pk2(lds[(p0 + 4) * 132 + c], lds[(p0 + 5) * 132 + c]);
  u0.w = pk2(lds[(p0 + 6) * 132 + c], lds[(p0 + 7) * 132 + c]);
  u1.x = pk2(lds[(p0 + 8) * 132 + c], lds[(p0 + 9) * 132 + c]);
  u1.y = pk2(lds[(p0 + 10) * 132 + c], lds[(p0 + 11) * 132 + c]);
  u1.z = pk2(lds[(p0 + 12) * 132 + c], lds[(p0 + 13) * 132 + c]);
  u1.w = pk2(lds[(p0 + 14) * 132 + c], lds[(p0 + 15) * 132 + c]);
  *reinterpret_cast<uint4*>(dst) = u0;
  *reinterpret_cast<uint4*>(dst + 8) = u1;
}

// ---------- patchify conv as MFMA GEMM, K-split partials -------------------
// R3's PROVEN convgemm_mfma with A-loads swapped to contiguous reads from
// bf16 xT (b,128,4096). k-ordering unchanged: k = ci*SS + kh*SRV + kw.
// W = RAW fp32 sr weights (co, ci, kh, kw), fragments via cvt8f (R3 exact).
template <int SRV, int KSP>
__global__ __launch_bounds__(256) void convgemm_mfma(
    const unsigned short* __restrict__ xT, const float* __restrict__ W,
    float* __restrict__ part) {
  constexpr int WP = 64 / SRV;
  constexpr int M = WP * WP;
  constexpr int ROWS = B_ * M;
  constexpr int SS = SRV * SRV;
  constexpr int KTOT = 128 * SS;
  constexpr int LSS = (SRV == 8) ? 6 : 4;
  constexpr int LM = (SRV == 8) ? 6 : 8;
  constexpr int LWP = (SRV == 8) ? 3 : 4;
  const int t = threadIdx.x;
  const int wid = t >> 6, lane = t & 63;
  const int lrow = lane & 15, lk = (lane >> 4) << 3;
  const int r0 = blockIdx.x * 128 + wid * 32;
  const int kb0 = blockIdx.y * KSP;
  int rbase[2], pixoff[2];
#pragma unroll
  for (int m = 0; m < 2; m++) {
    int row = r0 + m * 16 + lrow;
    int b = row >> LM, p = row & (M - 1);
    int ph = p >> LWP, pw = p & (WP - 1);
    rbase[m] = b << 19;                      // b * 128 * 4096 (xT element base)
    pixoff[m] = (ph * SRV) * 64 + pw * SRV;  // patch origin pixel
  }
  f32x4 acc[2][8];
#pragma unroll
  for (int m = 0; m < 2; m++)
#pragma unroll
    for (int n = 0; n < 8; n++) acc[m][n] = (f32x4)(0.f);
  for (int k0 = 0; k0 < KSP; k0 += 32) {
    int k = kb0 + k0 + lk;          // multiple of 8
    int ci = k >> LSS;
    int rem = k & (SS - 1);         // multiple of 8
    short8v a[2], bf[8];
#pragma unroll
    for (int m = 0; m < 2; m++) {
      if constexpr (SRV == 8) {
        // kh = rem>>3 fixed, kw = 0..7 contiguous
        a[m] = *reinterpret_cast<const short8v*>(
            xT + (size_t)rbase[m] + ci * 4096 + pixoff[m] + (rem >> 3) * 64);
      } else {
        // two 4-runs: (kh0, kw 0..3) and (kh0+1, kw 0..3)
        int kh0 = rem >> 2;
        short4v lo = *reinterpret_cast<const short4v*>(
            xT + (size_t)rbase[m] + ci * 4096 + pixoff[m] + kh0 * 64);
        short4v hi = *reinterpret_cast<const short4v*>(
            xT + (size_t)rbase[m] + ci * 4096 + pixoff[m] + (kh0 + 1) * 64);
        short8v av;
        av[0] = lo[0]; av[1] = lo[1]; av[2] = lo[2]; av[3] = lo[3];
        av[4] = hi[0]; av[5] = hi[1]; av[6] = hi[2]; av[7] = hi[3];
        a[m] = av;
      }
    }
#pragma unroll
    for (int n = 0; n < 8; n++)
      bf[n] = cvt8f(W + (size_t)(n * 16 + lrow) * KTOT + k);
#pragma unroll
    for (int m = 0; m < 2; m++)
#pragma unroll
      for (int n = 0; n < 8; n++)
        acc[m][n] = __builtin_amdgcn_mfma_f32_16x16x32_bf16(a[m], bf[n],
                                                            acc[m][n], 0, 0, 0);
  }
  const int rr = (lane >> 4) << 2;
#pragma unroll
  for (int m = 0; m < 2; m++)
#pragma unroll
    for (int n = 0; n < 8; n++) {
      int c = n * 16 + lrow;
#pragma unroll
      for (int j = 0; j < 4; j++)
        part[((size_t)blockIdx.y * ROWS + r0 + m * 16 + rr + j) * 128 + c] =
            acc[m][n][j];
    }
}

// ------------- MFMA GEMM (R3 exact): out[r][c] = sum_k A[r][k] * W[c][k] ---
template <bool HAS_BIAS>
__global__ __launch_bounds__(256) void gemm_mfma(const float* __restrict__ A,
    const unsigned short* __restrict__ W, const float* __restrict__ bias,
    float* __restrict__ out) {
  const int t = threadIdx.x;
  const int wid = t >> 6, lane = t & 63;
  const int lrow = lane & 15, lk = (lane >> 4) << 3;
  const int r0 = blockIdx.x * 128 + wid * 32;
  f32x4 acc[2][8];
#pragma unroll
  for (int m = 0; m < 2; m++)
#pragma unroll
    for (int n = 0; n < 8; n++) acc[m][n] = (f32x4)(0.f);
#pragma unroll
  for (int k0 = 0; k0 < 128; k0 += 32) {
    short8v a[2], bf[8];
#pragma unroll
    for (int m = 0; m < 2; m++)
      a[m] = cvt8f(A + (size_t)(r0 + m * 16 + lrow) * 128 + k0 + lk);
#pragma unroll
    for (int n = 0; n < 8; n++)
      bf[n] = *reinterpret_cast<const short8v*>(
          W + (size_t)(n * 16 + lrow) * 128 + k0 + lk);
#pragma unroll
    for (int m = 0; m < 2; m++)
#pragma unroll
      for (int n = 0; n < 8; n++)
        acc[m][n] = __builtin_amdgcn_mfma_f32_16x16x32_bf16(a[m], bf[n],
                                                            acc[m][n], 0, 0, 0);
  }
  const int rr = (lane >> 4) << 2;
#pragma unroll
  for (int m = 0; m < 2; m++)
#pragma unroll
    for (int n = 0; n < 8; n++) {
      int c = n * 16 + lrow;
      float bv = HAS_BIAS ? bias[c] : 0.f;
#pragma unroll
      for (int j = 0; j < 4; j++)
        out[(size_t)(r0 + m * 16 + rr + j) * 128 + c] = acc[m][n][j] + bv;
    }
}

// ---- reduce K-split partials + conv bias, LayerNorm(128) + exact GELU -----
__global__ __launch_bounds__(128) void ln_gelu(const float* __restrict__ part,
    int nsplit, int rows, const float* __restrict__ cb,
    const float* __restrict__ g, const float* __restrict__ be,
    float* __restrict__ out) {
  const int row = blockIdx.x;
  const int t = threadIdx.x;
  float v = cb[t];
  for (int s = 0; s < nsplit; s++)
    v += part[((size_t)s * rows + row) * 128 + t];
  float sv = v, sq = v * v;
#pragma unroll
  for (int off = 32; off > 0; off >>= 1) {
    sv += __shfl_down(sv, off, 64);
    sq += __shfl_down(sq, off, 64);
  }
  __shared__ float red0[2], red1[2];
  if ((t & 63) == 0) {
    red0[t >> 6] = sv;
    red1[t >> 6] = sq;
  }
  __syncthreads();
  float mean = (red0[0] + red0[1]) * (1.f / 128.f);
  float var = (red1[0] + red1[1]) * (1.f / 128.f) - mean * mean;
  float y = (v - mean) * rsqrtf(var + 1e-5f) * g[t] + be[t];
  out[(size_t)row * 128 + t] = y * 0.5f * (1.f + erff(y * 0.70710678118f));
}

// --------- depthwise 3x3 (pad 1) on v; v' = v + conv (R3 exact) ------------
template <int WP>
__global__ __launch_bounds__(256) void dwconv(const float* __restrict__ kv,
    const float* __restrict__ lw, const float* __restrict__ lb,
    float* __restrict__ vp) {
  constexpr int M = WP * WP;
  constexpr int LM = (WP == 8) ? 6 : 8;
  constexpr int LWPc = (WP == 8) ? 3 : 4;
  int idx = blockIdx.x * 256 + threadIdx.x;
  int ch = idx & 63;
  int rest = idx >> 6;
  int m = rest & (M - 1);
  int bb = rest >> LM;
  int y = m >> LWPc, x0 = m & (WP - 1);
  float s = lb[ch];
#pragma unroll
  for (int ky = 0; ky < 3; ky++) {
    int yy = y + ky - 1;
    if (yy < 0 || yy >= WP) continue;
#pragma unroll
    for (int kx = 0; kx < 3; kx++) {
      int xx = x0 + kx - 1;
      if (xx < 0 || xx >= WP) continue;
      s += kv[((size_t)(bb * M + yy * WP + xx)) * 128 + 64 + ch] *
           lw[ch * 9 + ky * 3 + kx];
    }
  }
  vp[idx] = kv[((size_t)(bb * M + m)) * 128 + 64 + ch] + s;
}

// ------------- fused attention (R3 exact, all fp32) ------------------------
template <int M, int QOFF>
__global__ __launch_bounds__(256) void attn(const float* __restrict__ q,
    const float* __restrict__ kv, const float* __restrict__ vp,
    float* __restrict__ xcat) {
  __shared__ float k_s[M][32];
  __shared__ float v_s[M][32];
  const int t = threadIdx.x;
  const int h = blockIdx.y, b = blockIdx.z;
  const size_t bm = (size_t)b * M;
  for (int e = t; e < M * 32; e += 256) {
    int m = e >> 5, d = e & 31;
    k_s[m][d] = kv[(bm + m) * 128 + h * 32 + d];
    v_s[m][d] = vp[(bm + m) * 64 + h * 32 + d];
  }
  __syncthreads();
  const int n = blockIdx.x * 256 + t;
  const float4* qv =
      reinterpret_cast<const float4*>(&q[((size_t)b * N_ + n) * 128 + QOFF + h * 32]);
  float4 q4[8];
#pragma unroll
  for (int i = 0; i < 8; i++) q4[i] = qv[i];
  float l = 0.f;
  float acc[32];
#pragma unroll
  for (int i = 0; i < 32; i++) acc[i] = 0.f;
  const float scale = 0.17677669529663687f;  // 1/sqrt(32)
  for (int m = 0; m < M; m++) {
    const float4* kr = reinterpret_cast<const float4*>(&k_s[m][0]);
    float s = 0.f;
#pragma unroll
    for (int i = 0; i < 8; i++) {
      float4 k4 = kr[i];
      s += q4[i].x * k4.x + q4[i].y * k4.y + q4[i].z * k4.z + q4[i].w * k4.w;
    }
    float p = __expf(s * scale);
    l += p;
    const float4* vr = reinterpret_cast<const float4*>(&v_s[m][0]);
#pragma unroll
    for (int i = 0; i < 8; i++) {
      float4 v4 = vr[i];
      acc[4 * i + 0] += p * v4.x;
      acc[4 * i + 1] += p * v4.y;
      acc[4 * i + 2] += p * v4.z;
      acc[4 * i + 3] += p * v4.w;
    }
  }
  float inv = 1.f / l;
  float4* orow =
      reinterpret_cast<float4*>(&xcat[((size_t)b * N_ + n) * 128 + QOFF + h * 32]);
#pragma unroll
  for (int i = 0; i < 8; i++) {
    float4 o;
    o.x = acc[4 * i + 0] * inv;
    o.y = acc[4 * i + 1] * inv;
    o.z = acc[4 * i + 2] * inv;
    o.w = acc[4 * i + 3] * inv;
    orow[i] = o;
  }
}

extern "C" void kernel_launch(void* const* d_in, const int* in_sizes, int n_in,
                              void* d_out, int out_size, void* d_ws,
                              size_t ws_size, hipStream_t stream) {
  (void)in_sizes; (void)n_in; (void)out_size; (void)ws_size;
  const float* x      = (const float*)d_in[0];
  const float* q_w    = (const float*)d_in[1];
  const float* sr1_w  = (const float*)d_in[2];
  const float* sr1_b  = (const float*)d_in[3];
  const float* n1_g   = (const float*)d_in[4];
  const float* n1_b   = (const float*)d_in[5];
  const float* sr2_w  = (const float*)d_in[6];
  const float* sr2_b  = (const float*)d_in[7];
  const float* n2_g   = (const float*)d_in[8];
  const float* n2_b   = (const float*)d_in[9];
  const float* kv1_w  = (const float*)d_in[10];
  const float* kv2_w  = (const float*)d_in[11];
  const float* lc1_w  = (const float*)d_in[12];
  const float* lc1_b  = (const float*)d_in[13];
  const float* lc2_w  = (const float*)d_in[14];
  const float* lc2_b  = (const float*)d_in[15];
  const float* proj_w = (const float*)d_in[16];
  const float* proj_b = (const float*)d_in[17];

  char* w = (char*)d_ws;
  unsigned short* wq    = (unsigned short*)(w);             // 32 KB
  unsigned short* wkv1  = (unsigned short*)(w + 32768);
  unsigned short* wkv2  = (unsigned short*)(w + 65536);
  unsigned short* wproj = (unsigned short*)(w + 98304);     // ends 131072
  float* qbuf = (float*)(w + 131072);                       // 33.55 MB
  // xT aliases the FIRST 16.78 MB of qbuf (dead before q-gemm writes qbuf)
  unsigned short* xT = (unsigned short*)(w + 131072);       // 16.78 MB
  float* xcat = (float*)(w + 33685504);                     // 33.55 MB
  float* part1 = xcat;                                      // 32*1024*128 f32
  float* part2 = xcat + 4194304;                            // 8*4096*128 f32
  float* t1   = (float*)(w + 69468160);                     // 512 KB
  float* t2   = (float*)(w + 69992448);                     // 2 MB
  float* kv1  = (float*)(w + 72089600);                     // 512 KB
  float* kv2  = (float*)(w + 72613888);                     // 2 MB
  float* v1p  = (float*)(w + 74711040);                     // 256 KB
  float* v2p  = (float*)(w + 74973184);                     // 1 MB -> 76021760

  cvt_w<<<256, 256, 0, stream>>>(q_w, kv1_w, kv2_w, proj_w, wq, wkv1, wkv2, wproj);
  // x -> xT (b,128,4096) bf16
  transpose_bf<<<2048, 256, 0, stream>>>(x, xT);
  // patchify convs (R3-proven kernel, contiguous A-loads, K-split partials)
  convgemm_mfma<8, 256><<<dim3(8, 32), 256, 0, stream>>>(xT, sr1_w, part1);
  convgemm_mfma<4, 256><<<dim3(32, 8), 256, 0, stream>>>(xT, sr2_w, part2);
  // bias + LN + GELU (fp32)
  ln_gelu<<<1024, 128, 0, stream>>>(part1, 32, 1024, sr1_b, n1_g, n1_b, t1);
  ln_gelu<<<4096, 128, 0, stream>>>(part2, 8, 4096, sr2_b, n2_g, n2_b, t2);
  // q = x @ q_w^T (fp32 out; overwrites xT region, which is now dead)
  gemm_mfma<false><<<512, 256, 0, stream>>>(x, wq, nullptr, qbuf);
  // kv projections
  gemm_mfma<false><<<8, 256, 0, stream>>>(t1, wkv1, nullptr, kv1);
  gemm_mfma<false><<<32, 256, 0, stream>>>(t2, wkv2, nullptr, kv2);
  // local depthwise conv on v
  dwconv<8><<<256, 256, 0, stream>>>(kv1, lc1_w, lc1_b, v1p);
  dwconv<16><<<1024, 256, 0, stream>>>(kv2, lc2_w, lc2_b, v2p);
  // fused attention (fp32), writes xcat (partials dead after ln_gelu)
  attn<64, 0><<<dim3(16, 2, 16), 256, 0, stream>>>(qbuf, kv1, v1p, xcat);
  attn<256, 64><<<dim3(16, 2, 16), 256, 0, stream>>>(qbuf, kv2, v2p, xcat);
  // output projection
  gemm_mfma<true><<<512, 256, 0, stream>>>(xcat, wproj, proj_b, (float*)d_out);
}

// Round 8
// 188.528 us; speedup vs baseline: 2.4703x; 1.3644x over previous
//
#include <hip/hip_runtime.h>
#include <math.h>

#define B_ 16
#define N_ 4096

typedef __attribute__((ext_vector_type(8))) short short8v;
typedef __attribute__((ext_vector_type(4))) short short4v;
typedef __attribute__((ext_vector_type(4))) float f32x4;

__device__ __forceinline__ unsigned short f2bf(float f) {
  unsigned int u = __float_as_uint(f);
  return (unsigned short)((u + 0x7FFFu + ((u >> 16) & 1u)) >> 16);
}

// pack two fp32 -> one dword of two bf16 (lo = first, hi = second)
__device__ __forceinline__ unsigned int pk2(float a, float b) {
  return (unsigned int)f2bf(a) | ((unsigned int)f2bf(b) << 16);
}

// convert 8 consecutive fp32 -> bf16x8 fragment
__device__ __forceinline__ short8v cvt8f(const float* p) {
  float4 a = *reinterpret_cast<const float4*>(p);
  float4 b = *reinterpret_cast<const float4*>(p + 4);
  short8v r;
  r[0] = (short)f2bf(a.x); r[1] = (short)f2bf(a.y);
  r[2] = (short)f2bf(a.z); r[3] = (short)f2bf(a.w);
  r[4] = (short)f2bf(b.x); r[5] = (short)f2bf(b.y);
  r[6] = (short)f2bf(b.z); r[7] = (short)f2bf(b.w);
  return r;
}

// ---------------- square weights -> bf16 (R3 exact) ------------------------
__global__ __launch_bounds__(256) void cvt_w(const float* __restrict__ a,
    const float* __restrict__ b, const float* __restrict__ c,
    const float* __restrict__ d, unsigned short* __restrict__ wa,
    unsigned short* __restrict__ wb, unsigned short* __restrict__ wc,
    unsigned short* __restrict__ wd) {
  int i = blockIdx.x * 256 + threadIdx.x;
  int j = i & 16383;
  if (i < 16384) wa[j] = f2bf(a[j]);
  else if (i < 32768) wb[j] = f2bf(b[j]);
  else if (i < 49152) wc[j] = f2bf(c[j]);
  else wd[j] = f2bf(d[j]);
}

// ---- x (b,4096,128) fp32 -> xT (b,128,4096) bf16: xT[b][c][p] = x[b][p][c] --
__global__ __launch_bounds__(256) void transpose_bf(const float* __restrict__ x,
    unsigned short* __restrict__ xT) {
  __shared__ float lds[32 * 132];
  const int t = threadIdx.x;
  const int b = blockIdx.x >> 7, pt = blockIdx.x & 127;
  const int ptile = pt * 32;
  for (int i = t; i < 1024; i += 256) {
    int p = i >> 5, c4 = (i & 31) << 2;
    *reinterpret_cast<float4*>(&lds[p * 132 + c4]) =
        *reinterpret_cast<const float4*>(
            x + ((size_t)(b * 4096 + ptile + p)) * 128 + c4);
  }
  __syncthreads();
  const int c = t >> 1, p0 = (t & 1) * 16;
  unsigned short* dst = xT + (size_t)b * 524288 + c * 4096 + ptile + p0;
  uint4 u0, u1;
  u0.x = pk2(lds[(p0 + 0) * 132 + c], lds[(p0 + 1) * 132 + c]);
  u0.y = pk2(lds[(p0 + 2) * 132 + c], lds[(p0 + 3) * 132 + c]);
  u0.z = pk2(lds[(p0 + 4) * 132 + c], lds[(p0 + 5) * 132 + c]);
  u0.w = pk2(lds[(p0 + 6) * 132 + c], lds[(p0 + 7) * 132 + c]);
  u1.x = pk2(lds[(p0 + 8) * 132 + c], lds[(p0 + 9) * 132 + c]);
  u1.y = pk2(lds[(p0 + 10) * 132 + c], lds[(p0 + 11) * 132 + c]);
  u1.z = pk2(lds[(p0 + 12) * 132 + c], lds[(p0 + 13) * 132 + c]);
  u1.w = pk2(lds[(p0 + 14) * 132 + c], lds[(p0 + 15) * 132 + c]);
  *reinterpret_cast<uint4*>(dst) = u0;
  *reinterpret_cast<uint4*>(dst + 8) = u1;
}

// ---------- patchify conv as MFMA GEMM, K-split partials (R7 exact) --------
template <int SRV, int KSP>
__global__ __launch_bounds__(256) void convgemm_mfma(
    const unsigned short* __restrict__ xT, const float* __restrict__ W,
    float* __restrict__ part) {
  constexpr int WP = 64 / SRV;
  constexpr int M = WP * WP;
  constexpr int ROWS = B_ * M;
  constexpr int SS = SRV * SRV;
  constexpr int KTOT = 128 * SS;
  constexpr int LSS = (SRV == 8) ? 6 : 4;
  constexpr int LM = (SRV == 8) ? 6 : 8;
  constexpr int LWP = (SRV == 8) ? 3 : 4;
  const int t = threadIdx.x;
  const int wid = t >> 6, lane = t & 63;
  const int lrow = lane & 15, lk = (lane >> 4) << 3;
  const int r0 = blockIdx.x * 128 + wid * 32;
  const int kb0 = blockIdx.y * KSP;
  int rbase[2], pixoff[2];
#pragma unroll
  for (int m = 0; m < 2; m++) {
    int row = r0 + m * 16 + lrow;
    int b = row >> LM, p = row & (M - 1);
    int ph = p >> LWP, pw = p & (WP - 1);
    rbase[m] = b << 19;
    pixoff[m] = (ph * SRV) * 64 + pw * SRV;
  }
  f32x4 acc[2][8];
#pragma unroll
  for (int m = 0; m < 2; m++)
#pragma unroll
    for (int n = 0; n < 8; n++) acc[m][n] = (f32x4)(0.f);
  for (int k0 = 0; k0 < KSP; k0 += 32) {
    int k = kb0 + k0 + lk;
    int ci = k >> LSS;
    int rem = k & (SS - 1);
    short8v a[2], bf[8];
#pragma unroll
    for (int m = 0; m < 2; m++) {
      if constexpr (SRV == 8) {
        a[m] = *reinterpret_cast<const short8v*>(
            xT + (size_t)rbase[m] + ci * 4096 + pixoff[m] + (rem >> 3) * 64);
      } else {
        int kh0 = rem >> 2;
        short4v lo = *reinterpret_cast<const short4v*>(
            xT + (size_t)rbase[m] + ci * 4096 + pixoff[m] + kh0 * 64);
        short4v hi = *reinterpret_cast<const short4v*>(
            xT + (size_t)rbase[m] + ci * 4096 + pixoff[m] + (kh0 + 1) * 64);
        short8v av;
        av[0] = lo[0]; av[1] = lo[1]; av[2] = lo[2]; av[3] = lo[3];
        av[4] = hi[0]; av[5] = hi[1]; av[6] = hi[2]; av[7] = hi[3];
        a[m] = av;
      }
    }
#pragma unroll
    for (int n = 0; n < 8; n++)
      bf[n] = cvt8f(W + (size_t)(n * 16 + lrow) * KTOT + k);
#pragma unroll
    for (int m = 0; m < 2; m++)
#pragma unroll
      for (int n = 0; n < 8; n++)
        acc[m][n] = __builtin_amdgcn_mfma_f32_16x16x32_bf16(a[m], bf[n],
                                                            acc[m][n], 0, 0, 0);
  }
  const int rr = (lane >> 4) << 2;
#pragma unroll
  for (int m = 0; m < 2; m++)
#pragma unroll
    for (int n = 0; n < 8; n++) {
      int c = n * 16 + lrow;
#pragma unroll
      for (int j = 0; j < 4; j++)
        part[((size_t)blockIdx.y * ROWS + r0 + m * 16 + rr + j) * 128 + c] =
            acc[m][n][j];
    }
}

// ------------- MFMA GEMM (R3 exact): out[r][c] = sum_k A[r][k] * W[c][k] ---
template <bool HAS_BIAS>
__global__ __launch_bounds__(256) void gemm_mfma(const float* __restrict__ A,
    const unsigned short* __restrict__ W, const float* __restrict__ bias,
    float* __restrict__ out) {
  const int t = threadIdx.x;
  const int wid = t >> 6, lane = t & 63;
  const int lrow = lane & 15, lk = (lane >> 4) << 3;
  const int r0 = blockIdx.x * 128 + wid * 32;
  f32x4 acc[2][8];
#pragma unroll
  for (int m = 0; m < 2; m++)
#pragma unroll
    for (int n = 0; n < 8; n++) acc[m][n] = (f32x4)(0.f);
#pragma unroll
  for (int k0 = 0; k0 < 128; k0 += 32) {
    short8v a[2], bf[8];
#pragma unroll
    for (int m = 0; m < 2; m++)
      a[m] = cvt8f(A + (size_t)(r0 + m * 16 + lrow) * 128 + k0 + lk);
#pragma unroll
    for (int n = 0; n < 8; n++)
      bf[n] = *reinterpret_cast<const short8v*>(
          W + (size_t)(n * 16 + lrow) * 128 + k0 + lk);
#pragma unroll
    for (int m = 0; m < 2; m++)
#pragma unroll
      for (int n = 0; n < 8; n++)
        acc[m][n] = __builtin_amdgcn_mfma_f32_16x16x32_bf16(a[m], bf[n],
                                                            acc[m][n], 0, 0, 0);
  }
  const int rr = (lane >> 4) << 2;
#pragma unroll
  for (int m = 0; m < 2; m++)
#pragma unroll
    for (int n = 0; n < 8; n++) {
      int c = n * 16 + lrow;
      float bv = HAS_BIAS ? bias[c] : 0.f;
#pragma unroll
      for (int j = 0; j < 4; j++)
        out[(size_t)(r0 + m * 16 + rr + j) * 128 + c] = acc[m][n][j] + bv;
    }
}

// ---- reduce K-split partials + conv bias, LayerNorm(128) + exact GELU -----
__global__ __launch_bounds__(128) void ln_gelu(const float* __restrict__ part,
    int nsplit, int rows, const float* __restrict__ cb,
    const float* __restrict__ g, const float* __restrict__ be,
    float* __restrict__ out) {
  const int row = blockIdx.x;
  const int t = threadIdx.x;
  float v = cb[t];
  for (int s = 0; s < nsplit; s++)
    v += part[((size_t)s * rows + row) * 128 + t];
  float sv = v, sq = v * v;
#pragma unroll
  for (int off = 32; off > 0; off >>= 1) {
    sv += __shfl_down(sv, off, 64);
    sq += __shfl_down(sq, off, 64);
  }
  __shared__ float red0[2], red1[2];
  if ((t & 63) == 0) {
    red0[t >> 6] = sv;
    red1[t >> 6] = sq;
  }
  __syncthreads();
  float mean = (red0[0] + red0[1]) * (1.f / 128.f);
  float var = (red1[0] + red1[1]) * (1.f / 128.f) - mean * mean;
  float y = (v - mean) * rsqrtf(var + 1e-5f) * g[t] + be[t];
  out[(size_t)row * 128 + t] = y * 0.5f * (1.f + erff(y * 0.70710678118f));
}

// --------- depthwise 3x3 (pad 1) on v; v' = v + conv (R3 exact) ------------
template <int WP>
__global__ __launch_bounds__(256) void dwconv(const float* __restrict__ kv,
    const float* __restrict__ lw, const float* __restrict__ lb,
    float* __restrict__ vp) {
  constexpr int M = WP * WP;
  constexpr int LM = (WP == 8) ? 6 : 8;
  constexpr int LWPc = (WP == 8) ? 3 : 4;
  int idx = blockIdx.x * 256 + threadIdx.x;
  int ch = idx & 63;
  int rest = idx >> 6;
  int m = rest & (M - 1);
  int bb = rest >> LM;
  int y = m >> LWPc, x0 = m & (WP - 1);
  float s = lb[ch];
#pragma unroll
  for (int ky = 0; ky < 3; ky++) {
    int yy = y + ky - 1;
    if (yy < 0 || yy >= WP) continue;
#pragma unroll
    for (int kx = 0; kx < 3; kx++) {
      int xx = x0 + kx - 1;
      if (xx < 0 || xx >= WP) continue;
      s += kv[((size_t)(bb * M + yy * WP + xx)) * 128 + 64 + ch] *
           lw[ch * 9 + ky * 3 + kx];
    }
  }
  vp[idx] = kv[((size_t)(bb * M + m)) * 128 + 64 + ch] + s;
}

// ------------- MFMA fused attention --------------------------------------
// Per block: 64 q-rows (4 waves x 16), one (b,h). S^T = mfma(K-rows, Q-rows)
// -> lane holds q-col lane&15, m-rows 4g+j. Softmax via 2 shfl_xor.
// PV: out^T = mfma(Vt-rows, P-rows), Vt/P in LDS (stride M+8: rows land in
// distinct bank-quads). Output scaled by 1/l, float4 stores.
template <int M, int QOFF>
__global__ __launch_bounds__(256) void attn_mfma(const float* __restrict__ q,
    const float* __restrict__ kv, const float* __restrict__ vp,
    float* __restrict__ xcat) {
  constexpr int PSTR = M + 8;    // elements; (M+8)/8 odd -> quad spread
  constexpr int MT = M / 16;     // S^T m-tiles
  constexpr int PVS = M / 32;    // PV k-steps
  __shared__ unsigned short Vt[32 * PSTR];
  __shared__ unsigned short Pl[4][16 * PSTR];
  const int t = threadIdx.x;
  const int wid = t >> 6, lane = t & 63;
  const int lrow = lane & 15, g = lane >> 4;
  const int lk = g * 8;
  const int h = blockIdx.y, b = blockIdx.z;
  const size_t bm = (size_t)b * M;
  // ---- stage V^T (bf16) ----
  for (int i = t; i < M * 8; i += 256) {
    int m = i >> 3, d4 = (i & 7) * 4;
    float4 vv = *reinterpret_cast<const float4*>(vp + (bm + m) * 64 + h * 32 + d4);
    Vt[(d4 + 0) * PSTR + m] = f2bf(vv.x);
    Vt[(d4 + 1) * PSTR + m] = f2bf(vv.y);
    Vt[(d4 + 2) * PSTR + m] = f2bf(vv.z);
    Vt[(d4 + 3) * PSTR + m] = f2bf(vv.w);
  }
  __syncthreads();
  // ---- Q fragment (16 q-rows per wave) ----
  const int q0 = blockIdx.x * 64 + wid * 16;
  short8v qf = cvt8f(q + ((size_t)b * 4096 + q0 + lrow) * 128 + QOFF + h * 32 + lk);
  // ---- S^T tiles: K fragments direct from global (L2-resident) ----
  f32x4 s[MT];
#pragma unroll
  for (int mt = 0; mt < MT; mt++) {
    short8v kf = cvt8f(kv + (bm + mt * 16 + lrow) * 128 + h * 32 + lk);
    s[mt] = __builtin_amdgcn_mfma_f32_16x16x32_bf16(kf, qf, (f32x4)(0.f), 0, 0, 0);
  }
  // ---- softmax over m (lane holds q-col lrow, m = mt*16 + 4g + j) ----
  const float scale = 0.17677669529663687f;  // 1/sqrt(32)
  float l = 0.f;
#pragma unroll
  for (int mt = 0; mt < MT; mt++)
#pragma unroll
    for (int j = 0; j < 4; j++) {
      float p = __expf(s[mt][j] * scale);
      s[mt][j] = p;
      l += p;
    }
  l += __shfl_xor(l, 16, 64);
  l += __shfl_xor(l, 32, 64);
  // ---- write P (bf16) to per-wave LDS: row = q-local, col = m ----
#pragma unroll
  for (int mt = 0; mt < MT; mt++) {
    uint2 pw;
    pw.x = pk2(s[mt][0], s[mt][1]);
    pw.y = pk2(s[mt][2], s[mt][3]);
    *reinterpret_cast<uint2*>(&Pl[wid][lrow * PSTR + mt * 16 + 4 * g]) = pw;
  }
  // ---- PV: out^T[d][q] accumulate ----
  f32x4 o[2];
  o[0] = (f32x4)(0.f);
  o[1] = (f32x4)(0.f);
#pragma unroll
  for (int ks = 0; ks < PVS; ks++) {
    short8v pf = *reinterpret_cast<const short8v*>(
        &Pl[wid][lrow * PSTR + ks * 32 + lk]);
#pragma unroll
    for (int dt = 0; dt < 2; dt++) {
      short8v vf = *reinterpret_cast<const short8v*>(
          &Vt[(dt * 16 + lrow) * PSTR + ks * 32 + lk]);
      o[dt] = __builtin_amdgcn_mfma_f32_16x16x32_bf16(vf, pf, o[dt], 0, 0, 0);
    }
  }
  // ---- store: lane holds q-col lrow, d-rows dt*16 + 4g + j ----
  float linv = 1.f / l;
  float* orow = xcat + ((size_t)b * 4096 + q0 + lrow) * 128 + QOFF + h * 32;
#pragma unroll
  for (int dt = 0; dt < 2; dt++) {
    float4 o4;
    o4.x = o[dt][0] * linv;
    o4.y = o[dt][1] * linv;
    o4.z = o[dt][2] * linv;
    o4.w = o[dt][3] * linv;
    *reinterpret_cast<float4*>(orow + dt * 16 + 4 * g) = o4;
  }
}

extern "C" void kernel_launch(void* const* d_in, const int* in_sizes, int n_in,
                              void* d_out, int out_size, void* d_ws,
                              size_t ws_size, hipStream_t stream) {
  (void)in_sizes; (void)n_in; (void)out_size; (void)ws_size;
  const float* x      = (const float*)d_in[0];
  const float* q_w    = (const float*)d_in[1];
  const float* sr1_w  = (const float*)d_in[2];
  const float* sr1_b  = (const float*)d_in[3];
  const float* n1_g   = (const float*)d_in[4];
  const float* n1_b   = (const float*)d_in[5];
  const float* sr2_w  = (const float*)d_in[6];
  const float* sr2_b  = (const float*)d_in[7];
  const float* n2_g   = (const float*)d_in[8];
  const float* n2_b   = (const float*)d_in[9];
  const float* kv1_w  = (const float*)d_in[10];
  const float* kv2_w  = (const float*)d_in[11];
  const float* lc1_w  = (const float*)d_in[12];
  const float* lc1_b  = (const float*)d_in[13];
  const float* lc2_w  = (const float*)d_in[14];
  const float* lc2_b  = (const float*)d_in[15];
  const float* proj_w = (const float*)d_in[16];
  const float* proj_b = (const float*)d_in[17];

  char* w = (char*)d_ws;
  unsigned short* wq    = (unsigned short*)(w);             // 32 KB
  unsigned short* wkv1  = (unsigned short*)(w + 32768);
  unsigned short* wkv2  = (unsigned short*)(w + 65536);
  unsigned short* wproj = (unsigned short*)(w + 98304);     // ends 131072
  float* qbuf = (float*)(w + 131072);                       // 33.55 MB
  unsigned short* xT = (unsigned short*)(w + 131072);       // aliases qbuf head
  float* xcat = (float*)(w + 33685504);                     // 33.55 MB
  float* part1 = xcat;
  float* part2 = xcat + 4194304;
  float* t1   = (float*)(w + 69468160);                     // 512 KB
  float* t2   = (float*)(w + 69992448);                     // 2 MB
  float* kv1  = (float*)(w + 72089600);                     // 512 KB
  float* kv2  = (float*)(w + 72613888);                     // 2 MB
  float* v1p  = (float*)(w + 74711040);                     // 256 KB
  float* v2p  = (float*)(w + 74973184);                     // 1 MB -> 76021760

  cvt_w<<<256, 256, 0, stream>>>(q_w, kv1_w, kv2_w, proj_w, wq, wkv1, wkv2, wproj);
  transpose_bf<<<2048, 256, 0, stream>>>(x, xT);
  convgemm_mfma<8, 256><<<dim3(8, 32), 256, 0, stream>>>(xT, sr1_w, part1);
  convgemm_mfma<4, 256><<<dim3(32, 8), 256, 0, stream>>>(xT, sr2_w, part2);
  ln_gelu<<<1024, 128, 0, stream>>>(part1, 32, 1024, sr1_b, n1_g, n1_b, t1);
  ln_gelu<<<4096, 128, 0, stream>>>(part2, 8, 4096, sr2_b, n2_g, n2_b, t2);
  gemm_mfma<false><<<512, 256, 0, stream>>>(x, wq, nullptr, qbuf);
  gemm_mfma<false><<<8, 256, 0, stream>>>(t1, wkv1, nullptr, kv1);
  gemm_mfma<false><<<32, 256, 0, stream>>>(t2, wkv2, nullptr, kv2);
  dwconv<8><<<256, 256, 0, stream>>>(kv1, lc1_w, lc1_b, v1p);
  dwconv<16><<<1024, 256, 0, stream>>>(kv2, lc2_w, lc2_b, v2p);
  // MFMA fused attention (bf16 compute, fp32 softmax/accum)
  attn_mfma<64, 0><<<dim3(64, 2, 16), 256, 0, stream>>>(qbuf, kv1, v1p, xcat);
  attn_mfma<256, 64><<<dim3(64, 2, 16), 256, 0, stream>>>(qbuf, kv2, v2p, xcat);
  gemm_mfma<true><<<512, 256, 0, stream>>>(xcat, wproj, proj_b, (float*)d_out);
}